// Round 1
// baseline (286.517 us; speedup 1.0000x reference)
//
#include <hip/hip_runtime.h>
#include <stdint.h>

typedef __attribute__((ext_vector_type(8))) short bf16x8;
typedef __attribute__((ext_vector_type(4))) float f32x4;

#define DW 147456        // per-member weight elems = 128*128*3*3
#define NTOT (6 * DW)    // U elems

__device__ __forceinline__ unsigned short f2bf(float f) {
    unsigned int u = __float_as_uint(f);
    u = (u + 0x7FFFu + ((u >> 16) & 1u)) >> 16;   // RNE, matches XLA f32->bf16
    return (unsigned short)u;
}

// ---------- 1) partial min/max reduction over U (float4) ----------
__global__ __launch_bounds__(256) void reduce_part(const float* __restrict__ U,
                                                   float* __restrict__ part) {
    int tid = threadIdx.x;
    float mx = -INFINITY, mn = INFINITY;
    const float4* U4 = (const float4*)U;
    for (int i = blockIdx.x * 256 + tid; i < NTOT / 4; i += 256 * 256) {
        float4 v = U4[i];
        mx = fmaxf(fmaxf(fmaxf(mx, v.x), v.y), fmaxf(v.z, v.w));
        mn = fminf(fminf(fminf(mn, v.x), v.y), fminf(v.z, v.w));
    }
    __shared__ float smx[256], smn[256];
    smx[tid] = mx; smn[tid] = mn;
    __syncthreads();
    for (int s = 128; s > 0; s >>= 1) {
        if (tid < s) {
            smx[tid] = fmaxf(smx[tid], smx[tid + s]);
            smn[tid] = fminf(smn[tid], smn[tid + s]);
        }
        __syncthreads();
    }
    if (tid == 0) { part[blockIdx.x] = smx[0]; part[256 + blockIdx.x] = smn[0]; }
}

// ---------- 2) weight synthesis (final reduce fused) -> bf16 ----------
// NEW Wb2 layout: [mem][c][och][t][mi][lane][j]  (lane = lq*16+lr, j = ch&7)
// so each (c,och,t) 4 KB tile is EXACTLY the lane-ordered MFMA A-fragment
// order -> conv's ds_read_b128 of Ws is contiguous in lane order (0 conflicts).
__global__ __launch_bounds__(256) void make_weights(const float* __restrict__ U,
                                                    const float* __restrict__ bp,
                                                    const float* __restrict__ uu,
                                                    const float* __restrict__ part,
                                                    unsigned short* __restrict__ Wb2) {
    int tid = threadIdx.x;
    __shared__ float smx[256], smn[256];
    smx[tid] = part[tid]; smn[tid] = part[256 + tid];
    __syncthreads();
    for (int s = 128; s > 0; s >>= 1) {
        if (tid < s) {
            smx[tid] = fmaxf(smx[tid], smx[tid + s]);
            smn[tid] = fminf(smn[tid], smn[tid + s]);
        }
        __syncthreads();
    }
    float beta = smx[0], alpha = smn[0];
    float s1 = (beta - alpha) / 3.0f;
    float s2 = s1 / 5.0f;

    int d = blockIdx.x * 256 + tid;

    float v1[6]; float Uv[6]; float vsum = 0.f;
    #pragma unroll
    for (int n = 0; n < 6; n++) {
        float Un = U[n * DW + d];
        Uv[n] = Un;
        float v = s1 * rintf(Un / s1);   // rintf = round-half-even = jnp.round
        v1[n] = v; vsum += v;
    }
    float vmean = vsum / 6.0f;

    // sigmoid(log(u/(1-u)) + b) == u / (u + (1-u)*exp(-b))  (saves the logf)
    float g6;
    {
        float un = uu[6 * DW + d];
        float sg = un / (un + (1.0f - un) * expf(-bp[6 * DW + d]));
        g6 = fminf(fmaxf(sg * 1.4f - 0.2f, 0.0f), 1.0f);
    }

    int oc = d / 1152;
    int rem = d - oc * 1152;
    int ic = rem / 9;
    int t9 = rem - ic * 9;
    int c = ic >> 5, icc = ic & 31;
    int och = oc >> 6, ocl = oc & 63;
    int mi = ocl >> 4, lrr = ocl & 15;
    int lq = icc >> 3, jj = icc & 7;
    size_t base = ((size_t)(c * 2 + och) * 9 + t9) * 2048
                + (size_t)mi * 512 + (size_t)(lq * 16 + lrr) * 8 + jj;

    #pragma unroll
    for (int n = 0; n < 6; n++) {
        float un = uu[n * DW + d];
        float sg = un / (un + (1.0f - un) * expf(-bp[n * DW + d]));
        float g0 = fminf(fmaxf(sg * 1.4f - 0.2f, 0.0f), 1.0f);
        float v2 = s2 * rintf((Uv[n] - vmean) / s2);
        float w = v1[n] * g0 + ((g0 > 0.0f && g6 > 0.0f) ? v2 * g6 : 0.0f);
        Wb2[(size_t)n * DW + base] = f2bf(w);
    }
}

// ---------- 3) NCHW fp32 -> [img][c(4)][row][col][32ch] bf16, slot-swizzled ----------
// Per column, the 4 channel-groups (8ch each) are stored at physical slot
// g ^ h where h = ((col_phys)>>1)&3 and col_phys = col+1 (Xs halo offset).
// This makes conv's strided-column ds_read_b128 hit 8 distinct bank-groups
// per 8 consecutive lanes (XOR-swizzle applied at the SOURCE, since
// global_load_lds writes LDS linearly -- rule #21).
__global__ __launch_bounds__(256) void transform_x(const float* __restrict__ x,
                                                   unsigned short* __restrict__ xT) {
    __shared__ unsigned short Sh[128 * 70];
    int b = blockIdx.x;
    int img = b >> 6, row = b & 63;
    int tid = threadIdx.x;
    {
        int ch = tid >> 1;
        int col0 = (tid & 1) * 32;
        const float* src = x + (((size_t)(img * 128 + ch) * 64 + row) * 64 + col0);
        #pragma unroll
        for (int j = 0; j < 8; j++) {
            float4 v = ((const float4*)src)[j];
            unsigned int p0 = (unsigned int)f2bf(v.x) | ((unsigned int)f2bf(v.y) << 16);
            unsigned int p1 = (unsigned int)f2bf(v.z) | ((unsigned int)f2bf(v.w) << 16);
            unsigned int* dst = (unsigned int*)&Sh[ch * 70 + col0 + j * 4];
            dst[0] = p0; dst[1] = p1;
        }
    }
    __syncthreads();
    {
        int col = tid & 63;
        int q = tid >> 6;            // chunk = wave index
        int chg = q * 32;
        int h = ((col + 1) >> 1) & 3;    // swizzle for Xs physical column col+1
        union { unsigned short s[32]; uint4 v[4]; } tmp;
        #pragma unroll
        for (int j = 0; j < 32; j++) tmp.s[j] = Sh[(chg + j) * 70 + col];
        // [img][q][row][col][32], channel-groups permuted by h (register perm,
        // stores stay fully coalesced)
        uint4* dst = (uint4*)(xT + ((size_t)img * 524288 + (size_t)q * 131072 +
                                    (size_t)row * 2048 + col * 32));
        #pragma unroll
        for (int k = 0; k < 4; k++) dst[k] = tmp.v[k ^ h];
    }
}

// ---------- 4) grouped conv: 64 oc x 512 px (8 rows) per block ----------
// 4 waves, each wave: 64 oc x 128 px (2 rows) => reads/MFMA = 16/64+16/128
// = 0.375 (was 0.5). All ds_read_b128 conflict-free: Ws lane-ordered,
// Xs slot-XOR-swizzled. LDS 79.1 KB -> 2 blocks/CU.
typedef const __attribute__((address_space(1))) void CGV;
typedef __attribute__((address_space(3))) void LV;

__global__ __launch_bounds__(256, 2) void conv_mfma(const unsigned short* __restrict__ xT,
                                                    const unsigned short* __restrict__ Wb2,
                                                    float* __restrict__ out) {
    __shared__ __align__(16) unsigned short Xs[10 * 66 * 32];   // 42240 B
    __shared__ __align__(16) unsigned short Ws[9 * 64 * 32];    // 36864 B
    // XCD-chunked bijective swizzle (768 % 8 == 0): one image's 16 blocks
    // stay on one XCD's L2.
    int o = blockIdx.x;
    int blk = (o & 7) * 96 + (o >> 3);
    int band = blk & 7;             // 8 bands of 8 output rows
    int och = (blk >> 3) & 1;       // oc half
    int img = blk >> 4;
    int row0 = band * 8;
    int mem = img - (img / 6) * 6;
    const unsigned short* Wmem = Wb2 + (size_t)mem * DW;
    const unsigned short* Xsrc = xT + (size_t)img * 524288;

    int tid = threadIdx.x;
    int lane = tid & 63;
    int w = tid >> 6;               // wave = 2 output rows
    int lr = lane & 15, lq = lane >> 4;
    // swizzled channel-slot offsets for dx = 0,1,2 (invariant under col+16)
    int so0 = (lq ^ ((lr >> 1) & 3)) * 8;
    int so1 = (lq ^ (((lr + 1) >> 1) & 3)) * 8;
    int so2 = (lq ^ (((lr + 2) >> 1) & 3)) * 8;

    // zero the halo border columns (col 0 and 65) once; never overwritten
    for (int i = tid; i < 320; i += 256) {
        int r = i >> 5, j = i & 31;
        int col = (j < 16) ? 0 : 65;
        *(unsigned int*)&Xs[(r * 66 + col) * 32 + (j & 15) * 2] = 0u;
    }

    auto stage = [&](int c) {
        // W: 9 taps x 4KB, contiguous lane-ordered ([c][och][t][mi][lane][8])
        const unsigned short* wsrc = Wmem + (size_t)((c * 2 + och) * 9) * 2048;
        #pragma unroll
        for (int t = 0; t < 9; t++)
            __builtin_amdgcn_global_load_lds((CGV*)(wsrc + t * 2048 + tid * 8),
                                             (LV*)(&Ws[t * 2048 + tid * 8]), 16, 0, 0);
        // X: 10 halo rows x 4KB contiguous (chunk-major, pre-swizzled slots)
        #pragma unroll
        for (int r = 0; r < 10; r++) {
            int srow = row0 + r - 1;
            if ((unsigned)srow < 64u)
                __builtin_amdgcn_global_load_lds((CGV*)(Xsrc + c * 131072 + srow * 2048 + tid * 8),
                                                 (LV*)(&Xs[(r * 66 + 1) * 32 + tid * 8]), 16, 0, 0);
            else
                *(uint4*)&Xs[(r * 66 + 1) * 32 + tid * 8] = make_uint4(0u, 0u, 0u, 0u);
        }
    };

    f32x4 acc[4][8];
    #pragma unroll
    for (int mi = 0; mi < 4; mi++)
        #pragma unroll
        for (int ni = 0; ni < 8; ni++)
            acc[mi][ni] = (f32x4){0.f, 0.f, 0.f, 0.f};

    stage(0);
    __syncthreads();

    for (int c = 0; c < 4; c++) {
        #pragma unroll
        for (int t = 0; t < 9; t++) {
            const int dy = t / 3, dx = t - (t / 3) * 3;
            const int so = (dx == 0) ? so0 : (dx == 1) ? so1 : so2;
            bf16x8 af[4], bfr[8];
            #pragma unroll
            for (int mi = 0; mi < 4; mi++)
                af[mi] = *(const bf16x8*)(&Ws[t * 2048 + mi * 512 + lane * 8]);
            #pragma unroll
            for (int ni = 0; ni < 8; ni++) {
                int xrow = w * 2 + (ni >> 2) + dy;
                int col = (ni & 3) * 16 + lr + dx;
                bfr[ni] = *(const bf16x8*)(&Xs[(xrow * 66 + col) * 32 + so]);
            }
            #pragma unroll
            for (int mi = 0; mi < 4; mi++)
                #pragma unroll
                for (int ni = 0; ni < 8; ni++)
                    acc[mi][ni] = __builtin_amdgcn_mfma_f32_16x16x32_bf16(
                        af[mi], bfr[ni], acc[mi][ni], 0, 0, 0);
        }
        if (c < 3) {
            __syncthreads();     // all waves done with Xs/Ws
            stage(c + 1);
            __syncthreads();     // staging landed (compiler drains vmcnt)
        }
    }

    // epilogue: C/D layout col=lane&15 (=px col), row=lq*4+reg (=oc)
    float* obase = out + (size_t)img * 524288;
    #pragma unroll
    for (int mi = 0; mi < 4; mi++) {
        #pragma unroll
        for (int ni = 0; ni < 8; ni++) {
            int r = row0 + w * 2 + (ni >> 2);
            int px = (ni & 3) * 16 + lr;
            int ocb = och * 64 + mi * 16 + lq * 4;
            #pragma unroll
            for (int rr = 0; rr < 4; rr++)
                obase[(size_t)(ocb + rr) * 4096 + (size_t)r * 64 + px] = acc[mi][ni][rr];
        }
    }
}

extern "C" void kernel_launch(void* const* d_in, const int* in_sizes, int n_in,
                              void* d_out, int out_size, void* d_ws, size_t ws_size,
                              hipStream_t stream) {
    const float* x  = (const float*)d_in[0];
    const float* U  = (const float*)d_in[1];
    const float* bp = (const float*)d_in[2];
    const float* uu = (const float*)d_in[3];
    float* out = (float*)d_out;

    char* ws = (char*)d_ws;
    float* part = (float*)ws;                                     // 512 floats
    unsigned short* Wb2 = (unsigned short*)(ws + 4096);           // 1,769,472 B
    unsigned short* xT  = (unsigned short*)(ws + 4096 + 1769472); // 50,331,648 B

    reduce_part <<<256, 256, 0, stream>>>(U, part);
    make_weights<<<576, 256, 0, stream>>>(U, bp, uu, part, Wb2);
    transform_x <<<48 * 64, 256, 0, stream>>>(x, xT);
    conv_mfma   <<<48 * 16, 256, 0, stream>>>(xT, Wb2, out);
}

// Round 2
// 266.518 us; speedup vs baseline: 1.0750x; 1.0750x over previous
//
#include <hip/hip_runtime.h>
#include <stdint.h>

typedef __attribute__((ext_vector_type(8))) short bf16x8;
typedef __attribute__((ext_vector_type(4))) float f32x4;

#define DW 147456        // per-member weight elems = 128*128*3*3
#define NTOT (6 * DW)    // U elems

__device__ __forceinline__ unsigned short f2bf(float f) {
    unsigned int u = __float_as_uint(f);
    u = (u + 0x7FFFu + ((u >> 16) & 1u)) >> 16;   // RNE, matches XLA f32->bf16
    return (unsigned short)u;
}

// ---------- 1) partial min/max reduction over U (float4) ----------
__global__ __launch_bounds__(256) void reduce_part(const float* __restrict__ U,
                                                   float* __restrict__ part) {
    int tid = threadIdx.x;
    float mx = -INFINITY, mn = INFINITY;
    const float4* U4 = (const float4*)U;
    for (int i = blockIdx.x * 256 + tid; i < NTOT / 4; i += 256 * 256) {
        float4 v = U4[i];
        mx = fmaxf(fmaxf(fmaxf(mx, v.x), v.y), fmaxf(v.z, v.w));
        mn = fminf(fminf(fminf(mn, v.x), v.y), fminf(v.z, v.w));
    }
    __shared__ float smx[256], smn[256];
    smx[tid] = mx; smn[tid] = mn;
    __syncthreads();
    for (int s = 128; s > 0; s >>= 1) {
        if (tid < s) {
            smx[tid] = fmaxf(smx[tid], smx[tid + s]);
            smn[tid] = fminf(smn[tid], smn[tid + s]);
        }
        __syncthreads();
    }
    if (tid == 0) { part[blockIdx.x] = smx[0]; part[256 + blockIdx.x] = smn[0]; }
}

// ---------- 2) weight synthesis (final reduce fused) -> bf16 ----------
// Wb2 layout: [mem][c][och][t][mi][lane][j]  (lane = lq*16+lr, j = ch&7)
// so each (c,och,t) 4 KB tile is EXACTLY the lane-ordered MFMA A-fragment
// order -> conv's ds_read_b128 of Ws is contiguous in lane order (0 conflicts).
__global__ __launch_bounds__(256) void make_weights(const float* __restrict__ U,
                                                    const float* __restrict__ bp,
                                                    const float* __restrict__ uu,
                                                    const float* __restrict__ part,
                                                    unsigned short* __restrict__ Wb2) {
    int tid = threadIdx.x;
    __shared__ float smx[256], smn[256];
    smx[tid] = part[tid]; smn[tid] = part[256 + tid];
    __syncthreads();
    for (int s = 128; s > 0; s >>= 1) {
        if (tid < s) {
            smx[tid] = fmaxf(smx[tid], smx[tid + s]);
            smn[tid] = fminf(smn[tid], smn[tid + s]);
        }
        __syncthreads();
    }
    float beta = smx[0], alpha = smn[0];
    float s1 = (beta - alpha) / 3.0f;
    float s2 = s1 / 5.0f;

    int d = blockIdx.x * 256 + tid;

    float v1[6]; float Uv[6]; float vsum = 0.f;
    #pragma unroll
    for (int n = 0; n < 6; n++) {
        float Un = U[n * DW + d];
        Uv[n] = Un;
        float v = s1 * rintf(Un / s1);   // rintf = round-half-even = jnp.round
        v1[n] = v; vsum += v;
    }
    float vmean = vsum / 6.0f;

    // sigmoid(log(u/(1-u)) + b) == u / (u + (1-u)*exp(-b))  (saves the logf)
    float g6;
    {
        float un = uu[6 * DW + d];
        float sg = un / (un + (1.0f - un) * expf(-bp[6 * DW + d]));
        g6 = fminf(fmaxf(sg * 1.4f - 0.2f, 0.0f), 1.0f);
    }

    int oc = d / 1152;
    int rem = d - oc * 1152;
    int ic = rem / 9;
    int t9 = rem - ic * 9;
    int c = ic >> 5, icc = ic & 31;
    int och = oc >> 6, ocl = oc & 63;
    int mi = ocl >> 4, lrr = ocl & 15;
    int lq = icc >> 3, jj = icc & 7;
    size_t base = ((size_t)(c * 2 + och) * 9 + t9) * 2048
                + (size_t)mi * 512 + (size_t)(lq * 16 + lrr) * 8 + jj;

    #pragma unroll
    for (int n = 0; n < 6; n++) {
        float un = uu[n * DW + d];
        float sg = un / (un + (1.0f - un) * expf(-bp[n * DW + d]));
        float g0 = fminf(fmaxf(sg * 1.4f - 0.2f, 0.0f), 1.0f);
        float v2 = s2 * rintf((Uv[n] - vmean) / s2);
        float w = v1[n] * g0 + ((g0 > 0.0f && g6 > 0.0f) ? v2 * g6 : 0.0f);
        Wb2[(size_t)n * DW + base] = f2bf(w);
    }
}

// ---------- 3) NCHW fp32 -> [img][c(4)][row][col][32ch] bf16, slot-swizzled ----------
// Per column, the 4 channel-groups (8ch each) are stored at physical slot
// g ^ h where h = ((col_phys)>>1)&3 and col_phys = col+1 (Xs halo offset).
// This makes conv's strided-column ds_read_b128 hit 8 distinct bank-groups
// per 8 consecutive lanes (XOR-swizzle applied at the SOURCE, since
// global_load_lds writes LDS linearly -- rule #21).
__global__ __launch_bounds__(256) void transform_x(const float* __restrict__ x,
                                                   unsigned short* __restrict__ xT) {
    __shared__ unsigned short Sh[128 * 70];
    int b = blockIdx.x;
    int img = b >> 6, row = b & 63;
    int tid = threadIdx.x;
    {
        int ch = tid >> 1;
        int col0 = (tid & 1) * 32;
        const float* src = x + (((size_t)(img * 128 + ch) * 64 + row) * 64 + col0);
        #pragma unroll
        for (int j = 0; j < 8; j++) {
            float4 v = ((const float4*)src)[j];
            unsigned int p0 = (unsigned int)f2bf(v.x) | ((unsigned int)f2bf(v.y) << 16);
            unsigned int p1 = (unsigned int)f2bf(v.z) | ((unsigned int)f2bf(v.w) << 16);
            unsigned int* dst = (unsigned int*)&Sh[ch * 70 + col0 + j * 4];
            dst[0] = p0; dst[1] = p1;
        }
    }
    __syncthreads();
    {
        int col = tid & 63;
        int q = tid >> 6;            // chunk = wave index
        int chg = q * 32;
        int h = ((col + 1) >> 1) & 3;    // swizzle for Xs physical column col+1
        union { unsigned short s[32]; uint4 v[4]; } tmp;
        #pragma unroll
        for (int j = 0; j < 32; j++) tmp.s[j] = Sh[(chg + j) * 70 + col];
        // [img][q][row][col][32], channel-groups permuted by h (register perm,
        // stores stay fully coalesced)
        uint4* dst = (uint4*)(xT + ((size_t)img * 524288 + (size_t)q * 131072 +
                                    (size_t)row * 2048 + col * 32));
        #pragma unroll
        for (int k = 0; k < 4; k++) dst[k] = tmp.v[k ^ h];
    }
}

// ---------- 4) grouped conv: 64 oc x 256 px (4 rows) per block ----------
// Round-0 occupancy geometry (grid 1536 = 6/CU, 2 resident, 3 FULL rounds,
// no tail) + round-1 conflict-free LDS layouts (Ws lane-ordered, Xs
// slot-XOR-swizzled). LDS 62.2 KB -> 2 blocks/CU.
typedef const __attribute__((address_space(1))) void CGV;
typedef __attribute__((address_space(3))) void LV;

__global__ __launch_bounds__(256, 2) void conv_mfma(const unsigned short* __restrict__ xT,
                                                    const unsigned short* __restrict__ Wb2,
                                                    float* __restrict__ out) {
    __shared__ __align__(16) unsigned short Xs[6 * 66 * 32];   // 25344 B
    __shared__ __align__(16) unsigned short Ws[9 * 64 * 32];   // 36864 B
    // XCD-chunked bijective swizzle (1536 % 8 == 0): one image's 32 blocks
    // stay on one XCD's L2.
    int o = blockIdx.x;
    int blk = (o & 7) * 192 + (o >> 3);
    int band = blk & 15;            // 16 bands of 4 output rows
    int och = (blk >> 4) & 1;       // oc half
    int img = blk >> 5;
    int row0 = band * 4;
    int mem = img - (img / 6) * 6;
    const unsigned short* Wmem = Wb2 + (size_t)mem * DW;
    const unsigned short* Xsrc = xT + (size_t)img * 524288;

    int tid = threadIdx.x;
    int lane = tid & 63;
    int prow = tid >> 6;            // wave = one of 4 output rows
    int lr = lane & 15, lq = lane >> 4;
    // swizzled channel-slot offsets for dx = 0,1,2 (invariant under col+16)
    int so0 = (lq ^ ((lr >> 1) & 3)) * 8;
    int so1 = (lq ^ (((lr + 1) >> 1) & 3)) * 8;
    int so2 = (lq ^ (((lr + 2) >> 1) & 3)) * 8;

    // zero the halo border columns (col 0 and 65) once; never overwritten
    if (tid < 192) {
        int r = tid >> 5, j = tid & 31;
        int col = (j < 16) ? 0 : 65;
        *(unsigned int*)&Xs[(r * 66 + col) * 32 + (j & 15) * 2] = 0u;
    }

    auto stage = [&](int c) {
        // W: 9 taps x 2KB, contiguous lane-ordered ([c][och][t][mi][lane][8])
        const unsigned short* wsrc = Wmem + (size_t)((c * 2 + och) * 9) * 2048;
        #pragma unroll
        for (int t = 0; t < 9; t++)
            __builtin_amdgcn_global_load_lds((CGV*)(wsrc + t * 2048 + tid * 8),
                                             (LV*)(&Ws[t * 2048 + tid * 8]), 16, 0, 0);
        // X: 6 halo rows x 4KB contiguous (chunk-major, pre-swizzled slots)
        #pragma unroll
        for (int r = 0; r < 6; r++) {
            int srow = row0 + r - 1;
            if ((unsigned)srow < 64u)
                __builtin_amdgcn_global_load_lds((CGV*)(Xsrc + c * 131072 + srow * 2048 + tid * 8),
                                                 (LV*)(&Xs[(r * 66 + 1) * 32 + tid * 8]), 16, 0, 0);
            else
                *(uint4*)&Xs[(r * 66 + 1) * 32 + tid * 8] = make_uint4(0u, 0u, 0u, 0u);
        }
    };

    f32x4 acc[4][4];
    #pragma unroll
    for (int mi = 0; mi < 4; mi++)
        #pragma unroll
        for (int ni = 0; ni < 4; ni++)
            acc[mi][ni] = (f32x4){0.f, 0.f, 0.f, 0.f};

    stage(0);
    __syncthreads();

    for (int c = 0; c < 4; c++) {
        #pragma unroll
        for (int t = 0; t < 9; t++) {
            const int dy = t / 3, dx = t - (t / 3) * 3;
            const int so = (dx == 0) ? so0 : (dx == 1) ? so1 : so2;
            bf16x8 af[4], bfr[4];
            #pragma unroll
            for (int mi = 0; mi < 4; mi++)
                af[mi] = *(const bf16x8*)(&Ws[t * 2048 + mi * 512 + lane * 8]);
            #pragma unroll
            for (int ni = 0; ni < 4; ni++) {
                int col = ni * 16 + lr + dx;
                bfr[ni] = *(const bf16x8*)(&Xs[((prow + dy) * 66 + col) * 32 + so]);
            }
            #pragma unroll
            for (int mi = 0; mi < 4; mi++)
                #pragma unroll
                for (int ni = 0; ni < 4; ni++)
                    acc[mi][ni] = __builtin_amdgcn_mfma_f32_16x16x32_bf16(
                        af[mi], bfr[ni], acc[mi][ni], 0, 0, 0);
        }
        if (c < 3) {
            __syncthreads();     // all waves done with Xs/Ws
            stage(c + 1);
            __syncthreads();     // staging landed (compiler drains vmcnt)
        }
    }

    // epilogue: C/D layout col=lane&15 (=px col), row=lq*4+reg (=oc)
    float* obase = out + (size_t)img * 524288 + (size_t)(row0 + prow) * 64;
    #pragma unroll
    for (int mi = 0; mi < 4; mi++) {
        #pragma unroll
        for (int ni = 0; ni < 4; ni++) {
            int px = ni * 16 + lr;
            int ocb = och * 64 + mi * 16 + lq * 4;
            #pragma unroll
            for (int rr = 0; rr < 4; rr++)
                obase[(size_t)(ocb + rr) * 4096 + px] = acc[mi][ni][rr];
        }
    }
}

extern "C" void kernel_launch(void* const* d_in, const int* in_sizes, int n_in,
                              void* d_out, int out_size, void* d_ws, size_t ws_size,
                              hipStream_t stream) {
    const float* x  = (const float*)d_in[0];
    const float* U  = (const float*)d_in[1];
    const float* bp = (const float*)d_in[2];
    const float* uu = (const float*)d_in[3];
    float* out = (float*)d_out;

    char* ws = (char*)d_ws;
    float* part = (float*)ws;                                     // 512 floats
    unsigned short* Wb2 = (unsigned short*)(ws + 4096);           // 1,769,472 B
    unsigned short* xT  = (unsigned short*)(ws + 4096 + 1769472); // 50,331,648 B

    reduce_part <<<256, 256, 0, stream>>>(U, part);
    make_weights<<<576, 256, 0, stream>>>(U, bp, uu, part, Wb2);
    transform_x <<<48 * 64, 256, 0, stream>>>(x, xT);
    conv_mfma   <<<48 * 32, 256, 0, stream>>>(xT, Wb2, out);
}

// Round 3
// 251.291 us; speedup vs baseline: 1.1402x; 1.0606x over previous
//
#include <hip/hip_runtime.h>
#include <stdint.h>

typedef __attribute__((ext_vector_type(8))) short bf16x8;
typedef __attribute__((ext_vector_type(4))) float f32x4;

#define DW 147456        // per-member weight elems = 128*128*3*3
#define NTOT (6 * DW)    // U elems

__device__ __forceinline__ unsigned short f2bf(float f) {
    unsigned int u = __float_as_uint(f);
    u = (u + 0x7FFFu + ((u >> 16) & 1u)) >> 16;   // RNE, matches XLA f32->bf16
    return (unsigned short)u;
}

// ---------- 1) partial min/max reduction over U (float4) ----------
__global__ __launch_bounds__(256) void reduce_part(const float* __restrict__ U,
                                                   float* __restrict__ part) {
    int tid = threadIdx.x;
    float mx = -INFINITY, mn = INFINITY;
    const float4* U4 = (const float4*)U;
    for (int i = blockIdx.x * 256 + tid; i < NTOT / 4; i += 256 * 256) {
        float4 v = U4[i];
        mx = fmaxf(fmaxf(fmaxf(mx, v.x), v.y), fmaxf(v.z, v.w));
        mn = fminf(fminf(fminf(mn, v.x), v.y), fminf(v.z, v.w));
    }
    __shared__ float smx[256], smn[256];
    smx[tid] = mx; smn[tid] = mn;
    __syncthreads();
    for (int s = 128; s > 0; s >>= 1) {
        if (tid < s) {
            smx[tid] = fmaxf(smx[tid], smx[tid + s]);
            smn[tid] = fminf(smn[tid], smn[tid + s]);
        }
        __syncthreads();
    }
    if (tid == 0) { part[blockIdx.x] = smx[0]; part[256 + blockIdx.x] = smn[0]; }
}

// ---------- 2) weight synthesis (final reduce fused) -> bf16 ----------
// Wb2 layout: [mem][c][och][t][mi][lane][j]  (lane = lq*16+lr, j = ch&7)
// so each (c,och,t) 4 KB tile is EXACTLY the lane-ordered MFMA A-fragment
// order -> conv's ds_read_b128 of Ws is contiguous in lane order (0 conflicts).
__global__ __launch_bounds__(256) void make_weights(const float* __restrict__ U,
                                                    const float* __restrict__ bp,
                                                    const float* __restrict__ uu,
                                                    const float* __restrict__ part,
                                                    unsigned short* __restrict__ Wb2) {
    int tid = threadIdx.x;
    __shared__ float smx[256], smn[256];
    smx[tid] = part[tid]; smn[tid] = part[256 + tid];
    __syncthreads();
    for (int s = 128; s > 0; s >>= 1) {
        if (tid < s) {
            smx[tid] = fmaxf(smx[tid], smx[tid + s]);
            smn[tid] = fminf(smn[tid], smn[tid + s]);
        }
        __syncthreads();
    }
    float beta = smx[0], alpha = smn[0];
    float s1 = (beta - alpha) / 3.0f;
    float s2 = s1 / 5.0f;

    int d = blockIdx.x * 256 + tid;

    float v1[6]; float Uv[6]; float vsum = 0.f;
    #pragma unroll
    for (int n = 0; n < 6; n++) {
        float Un = U[n * DW + d];
        Uv[n] = Un;
        float v = s1 * rintf(Un / s1);   // rintf = round-half-even = jnp.round
        v1[n] = v; vsum += v;
    }
    float vmean = vsum / 6.0f;

    // sigmoid(log(u/(1-u)) + b) == u / (u + (1-u)*exp(-b))  (saves the logf)
    float g6;
    {
        float un = uu[6 * DW + d];
        float sg = un / (un + (1.0f - un) * expf(-bp[6 * DW + d]));
        g6 = fminf(fmaxf(sg * 1.4f - 0.2f, 0.0f), 1.0f);
    }

    int oc = d / 1152;
    int rem = d - oc * 1152;
    int ic = rem / 9;
    int t9 = rem - ic * 9;
    int c = ic >> 5, icc = ic & 31;
    int och = oc >> 6, ocl = oc & 63;
    int mi = ocl >> 4, lrr = ocl & 15;
    int lq = icc >> 3, jj = icc & 7;
    size_t base = ((size_t)(c * 2 + och) * 9 + t9) * 2048
                + (size_t)mi * 512 + (size_t)(lq * 16 + lrr) * 8 + jj;

    #pragma unroll
    for (int n = 0; n < 6; n++) {
        float un = uu[n * DW + d];
        float sg = un / (un + (1.0f - un) * expf(-bp[n * DW + d]));
        float g0 = fminf(fmaxf(sg * 1.4f - 0.2f, 0.0f), 1.0f);
        float v2 = s2 * rintf((Uv[n] - vmean) / s2);
        float w = v1[n] * g0 + ((g0 > 0.0f && g6 > 0.0f) ? v2 * g6 : 0.0f);
        Wb2[(size_t)n * DW + base] = f2bf(w);
    }
}

// ---------- 3) NCHW fp32 -> [img][c(4)][row][col][32ch] bf16, slot-swizzled ----------
// Per column, the 4 channel-groups (8ch each) are stored at physical slot
// g ^ h where h = ((col_phys)>>1)&3 and col_phys = col+1 (Xs halo offset).
// XOR-permutation applied via COMPILE-TIME-indexed conditional swaps
// (rule #20: tmp.v[k^h] with runtime h goes to scratch -- round-2 regression).
__global__ __launch_bounds__(256) void transform_x(const float* __restrict__ x,
                                                   unsigned short* __restrict__ xT) {
    __shared__ unsigned short Sh[128 * 70];
    int b = blockIdx.x;
    int img = b >> 6, row = b & 63;
    int tid = threadIdx.x;
    {
        int ch = tid >> 1;
        int col0 = (tid & 1) * 32;
        const float* src = x + (((size_t)(img * 128 + ch) * 64 + row) * 64 + col0);
        #pragma unroll
        for (int j = 0; j < 8; j++) {
            float4 v = ((const float4*)src)[j];
            unsigned int p0 = (unsigned int)f2bf(v.x) | ((unsigned int)f2bf(v.y) << 16);
            unsigned int p1 = (unsigned int)f2bf(v.z) | ((unsigned int)f2bf(v.w) << 16);
            unsigned int* dst = (unsigned int*)&Sh[ch * 70 + col0 + j * 4];
            dst[0] = p0; dst[1] = p1;
        }
    }
    __syncthreads();
    {
        int col = tid & 63;
        int q = tid >> 6;            // chunk = wave index
        int chg = q * 32;
        int h = ((col + 1) >> 1) & 3;    // swizzle for Xs physical column col+1
        union { unsigned short s[32]; uint4 v[4]; } tmp;
        #pragma unroll
        for (int j = 0; j < 32; j++) tmp.s[j] = Sh[(chg + j) * 70 + col];
        // out[k] = tmp.v[k ^ h] via two conditional swap layers (all indices
        // compile-time constant -> stays in VGPRs)
        uint4 a = tmp.v[0], bb = tmp.v[1], c2 = tmp.v[2], d2 = tmp.v[3];
        if (h & 1) { uint4 t = a; a = bb; bb = t; t = c2; c2 = d2; d2 = t; }
        if (h & 2) { uint4 t = a; a = c2; c2 = t; t = bb; bb = d2; d2 = t; }
        // [img][q][row][col][32], channel-groups permuted by h (register perm,
        // stores stay fully coalesced)
        uint4* dst = (uint4*)(xT + ((size_t)img * 524288 + (size_t)q * 131072 +
                                    (size_t)row * 2048 + col * 32));
        dst[0] = a; dst[1] = bb; dst[2] = c2; dst[3] = d2;
    }
}

// ---------- 4) grouped conv: 64 oc x 256 px (4 rows) per block ----------
// Round-0 occupancy geometry (grid 1536 = 6/CU, 2 resident, 3 FULL rounds,
// no tail) + conflict-free LDS layouts (Ws lane-ordered, Xs
// slot-XOR-swizzled). LDS 62.2 KB -> 2 blocks/CU.
typedef const __attribute__((address_space(1))) void CGV;
typedef __attribute__((address_space(3))) void LV;

__global__ __launch_bounds__(256, 2) void conv_mfma(const unsigned short* __restrict__ xT,
                                                    const unsigned short* __restrict__ Wb2,
                                                    float* __restrict__ out) {
    __shared__ __align__(16) unsigned short Xs[6 * 66 * 32];   // 25344 B
    __shared__ __align__(16) unsigned short Ws[9 * 64 * 32];   // 36864 B
    // XCD-chunked bijective swizzle (1536 % 8 == 0): one image's 32 blocks
    // stay on one XCD's L2.
    int o = blockIdx.x;
    int blk = (o & 7) * 192 + (o >> 3);
    int band = blk & 15;            // 16 bands of 4 output rows
    int och = (blk >> 4) & 1;       // oc half
    int img = blk >> 5;
    int row0 = band * 4;
    int mem = img - (img / 6) * 6;
    const unsigned short* Wmem = Wb2 + (size_t)mem * DW;
    const unsigned short* Xsrc = xT + (size_t)img * 524288;

    int tid = threadIdx.x;
    int lane = tid & 63;
    int prow = tid >> 6;            // wave = one of 4 output rows
    int lr = lane & 15, lq = lane >> 4;
    // swizzled channel-slot offsets for dx = 0,1,2 (invariant under col+16)
    int so0 = (lq ^ ((lr >> 1) & 3)) * 8;
    int so1 = (lq ^ (((lr + 1) >> 1) & 3)) * 8;
    int so2 = (lq ^ (((lr + 2) >> 1) & 3)) * 8;

    // zero the halo border columns (col 0 and 65) once; never overwritten
    if (tid < 192) {
        int r = tid >> 5, j = tid & 31;
        int col = (j < 16) ? 0 : 65;
        *(unsigned int*)&Xs[(r * 66 + col) * 32 + (j & 15) * 2] = 0u;
    }

    auto stage = [&](int c) {
        // W: 9 taps x 2KB, contiguous lane-ordered ([c][och][t][mi][lane][8])
        const unsigned short* wsrc = Wmem + (size_t)((c * 2 + och) * 9) * 2048;
        #pragma unroll
        for (int t = 0; t < 9; t++)
            __builtin_amdgcn_global_load_lds((CGV*)(wsrc + t * 2048 + tid * 8),
                                             (LV*)(&Ws[t * 2048 + tid * 8]), 16, 0, 0);
        // X: 6 halo rows x 4KB contiguous (chunk-major, pre-swizzled slots)
        #pragma unroll
        for (int r = 0; r < 6; r++) {
            int srow = row0 + r - 1;
            if ((unsigned)srow < 64u)
                __builtin_amdgcn_global_load_lds((CGV*)(Xsrc + c * 131072 + srow * 2048 + tid * 8),
                                                 (LV*)(&Xs[(r * 66 + 1) * 32 + tid * 8]), 16, 0, 0);
            else
                *(uint4*)&Xs[(r * 66 + 1) * 32 + tid * 8] = make_uint4(0u, 0u, 0u, 0u);
        }
    };

    f32x4 acc[4][4];
    #pragma unroll
    for (int mi = 0; mi < 4; mi++)
        #pragma unroll
        for (int ni = 0; ni < 4; ni++)
            acc[mi][ni] = (f32x4){0.f, 0.f, 0.f, 0.f};

    stage(0);
    __syncthreads();

    for (int c = 0; c < 4; c++) {
        #pragma unroll
        for (int t = 0; t < 9; t++) {
            const int dy = t / 3, dx = t - (t / 3) * 3;
            const int so = (dx == 0) ? so0 : (dx == 1) ? so1 : so2;
            bf16x8 af[4], bfr[4];
            #pragma unroll
            for (int mi = 0; mi < 4; mi++)
                af[mi] = *(const bf16x8*)(&Ws[t * 2048 + mi * 512 + lane * 8]);
            #pragma unroll
            for (int ni = 0; ni < 4; ni++) {
                int col = ni * 16 + lr + dx;
                bfr[ni] = *(const bf16x8*)(&Xs[((prow + dy) * 66 + col) * 32 + so]);
            }
            #pragma unroll
            for (int mi = 0; mi < 4; mi++)
                #pragma unroll
                for (int ni = 0; ni < 4; ni++)
                    acc[mi][ni] = __builtin_amdgcn_mfma_f32_16x16x32_bf16(
                        af[mi], bfr[ni], acc[mi][ni], 0, 0, 0);
        }
        if (c < 3) {
            __syncthreads();     // all waves done with Xs/Ws
            stage(c + 1);
            __syncthreads();     // staging landed (compiler drains vmcnt)
        }
    }

    // epilogue: C/D layout col=lane&15 (=px col), row=lq*4+reg (=oc)
    float* obase = out + (size_t)img * 524288 + (size_t)(row0 + prow) * 64;
    #pragma unroll
    for (int mi = 0; mi < 4; mi++) {
        #pragma unroll
        for (int ni = 0; ni < 4; ni++) {
            int px = ni * 16 + lr;
            int ocb = och * 64 + mi * 16 + lq * 4;
            #pragma unroll
            for (int rr = 0; rr < 4; rr++)
                obase[(size_t)(ocb + rr) * 4096 + px] = acc[mi][ni][rr];
        }
    }
}

extern "C" void kernel_launch(void* const* d_in, const int* in_sizes, int n_in,
                              void* d_out, int out_size, void* d_ws, size_t ws_size,
                              hipStream_t stream) {
    const float* x  = (const float*)d_in[0];
    const float* U  = (const float*)d_in[1];
    const float* bp = (const float*)d_in[2];
    const float* uu = (const float*)d_in[3];
    float* out = (float*)d_out;

    char* ws = (char*)d_ws;
    float* part = (float*)ws;                                     // 512 floats
    unsigned short* Wb2 = (unsigned short*)(ws + 4096);           // 1,769,472 B
    unsigned short* xT  = (unsigned short*)(ws + 4096 + 1769472); // 50,331,648 B

    reduce_part <<<256, 256, 0, stream>>>(U, part);
    make_weights<<<576, 256, 0, stream>>>(U, bp, uu, part, Wb2);
    transform_x <<<48 * 64, 256, 0, stream>>>(x, xT);
    conv_mfma   <<<48 * 32, 256, 0, stream>>>(xT, Wb2, out);
}